// Round 6
// baseline (350.732 us; speedup 1.0000x reference)
//
#include <hip/hip_runtime.h>
#include <hip/hip_bf16.h>
#include <cstdint>
#include <cstddef>

#define NHEAD 12
#define TSEQ  4096
#define CDIM  768

typedef __attribute__((ext_vector_type(8))) short bf16x8;
typedef __attribute__((ext_vector_type(4))) float f32x4;
typedef __attribute__((ext_vector_type(16))) float f32x16;
typedef __attribute__((ext_vector_type(2))) unsigned int u32x2;

typedef __attribute__((address_space(1))) void gvoid;
typedef __attribute__((address_space(3))) void lvoid;

#define QSCALE 0.1803368801111204f   /* 0.125 * log2(e) */

static __device__ __forceinline__ unsigned short f2bf(float f) {
    union { float f; uint32_t u; } v; v.f = f;
    uint32_t u = v.u;
    u += 0x7fffu + ((u >> 16) & 1u);   // RNE
    return (unsigned short)(u >> 16);
}

static __device__ __forceinline__ f32x4 mfma16(bf16x8 a, bf16x8 b, f32x4 c) {
    return __builtin_amdgcn_mfma_f32_16x16x32_bf16(a, b, c, 0, 0, 0);
}
static __device__ __forceinline__ f32x16 mfma32(bf16x8 a, bf16x8 b, f32x16 c) {
    return __builtin_amdgcn_mfma_f32_32x32x16_bf16(a, b, c, 0, 0, 0);
}
static __device__ __forceinline__ unsigned cvt_pk_bf16(float lo, float hi) {
    unsigned r;
    asm("v_cvt_pk_bf16_f32 %0, %1, %2" : "=v"(r) : "v"(lo), "v"(hi));
    return r;
}

// ---------------- conversion kernels ----------------

__global__ void cvt_f32_bf16(const float* __restrict__ in, unsigned short* __restrict__ out, int n4) {
    int i = blockIdx.x * blockDim.x + threadIdx.x;
    int stride = gridDim.x * blockDim.x;
    for (int idx = i; idx < n4; idx += stride) {
        float4 v = reinterpret_cast<const float4*>(in)[idx];
        ushort4 o;
        o.x = f2bf(v.x); o.y = f2bf(v.y); o.z = f2bf(v.z); o.w = f2bf(v.w);
        reinterpret_cast<ushort4*>(out)[idx] = o;
    }
}

// W [K][N] f32  ->  Wt [N][K] bf16
__global__ void transpose_cvt(const float* __restrict__ W, unsigned short* __restrict__ Wt,
                              int K, int N) {
    __shared__ float tile[32][33];
    int n0 = blockIdx.x * 32;
    int k0 = blockIdx.y * 32;
    int tx = threadIdx.x & 31;
    int ty = threadIdx.x >> 5;   // 0..7
    #pragma unroll
    for (int r = ty; r < 32; r += 8)
        tile[r][tx] = W[(size_t)(k0 + r) * N + n0 + tx];
    __syncthreads();
    #pragma unroll
    for (int r = ty; r < 32; r += 8)
        Wt[(size_t)(n0 + r) * K + k0 + tx] = f2bf(tile[tx][r]);
}

// ---------------- GEMM core (A [M][K] bf16, Bt [N][K] bf16) ----------------
// MODE 0: qkv epilogue -> Q[h][t][d] (pre-scaled), K[h][t][d], Vt[h][d][t]
// MODE 1: proj epilogue -> Out f32 [M][N] (+bias)

template<int MODE>
__global__ __launch_bounds__(256)
void gemm_bt(const unsigned short* __restrict__ A,
             const unsigned short* __restrict__ Bt,
             const float* __restrict__ bias,
             unsigned short* __restrict__ Qb,
             unsigned short* __restrict__ Kb,
             unsigned short* __restrict__ Vt,
             float* __restrict__ Out,
             int M, int N, int K)
{
    __shared__ __align__(16) unsigned short As[128 * 32];
    __shared__ __align__(16) unsigned short Bs[128 * 32];

    const int tid  = threadIdx.x;
    const int lane = tid & 63;
    const int w    = tid >> 6;       // 4 waves
    const int wr   = w >> 1, wc = w & 1;
    const int row0 = blockIdx.x * 128;
    const int col0 = blockIdx.y * 128;
    const int l16  = lane & 15;
    const int lhi  = lane >> 4;

    f32x4 acc[4][4] = {};

    for (int k0 = 0; k0 < K; k0 += 32) {
        __syncthreads();
        #pragma unroll
        for (int r = 0; r < 2; ++r) {
            int b    = r * 4096 + w * 1024 + lane * 16;
            int trow = b >> 6;
            int koff = b & 63;
            const char* gA = (const char*)A  + ((size_t)(row0 + trow) * K + k0) * 2 + koff;
            const char* gB = (const char*)Bt + ((size_t)(col0 + trow) * K + k0) * 2 + koff;
            __builtin_amdgcn_global_load_lds((gvoid*)gA,
                (lvoid*)((char*)As + r * 4096 + w * 1024), 16, 0, 0);
            __builtin_amdgcn_global_load_lds((gvoid*)gB,
                (lvoid*)((char*)Bs + r * 4096 + w * 1024), 16, 0, 0);
        }
        __syncthreads();

        bf16x8 a[4], bfr[4];
        #pragma unroll
        for (int m = 0; m < 4; ++m) {
            int row = wr * 64 + m * 16 + l16;
            a[m] = *reinterpret_cast<const bf16x8*>(&As[row * 32 + lhi * 8]);
        }
        #pragma unroll
        for (int n = 0; n < 4; ++n) {
            int col = wc * 64 + n * 16 + l16;
            bfr[n] = *reinterpret_cast<const bf16x8*>(&Bs[col * 32 + lhi * 8]);
        }
        #pragma unroll
        for (int m = 0; m < 4; ++m)
            #pragma unroll
            for (int n = 0; n < 4; ++n)
                acc[m][n] = mfma16(a[m], bfr[n], acc[m][n]);
    }

    #pragma unroll
    for (int m = 0; m < 4; ++m) {
        int trow = row0 + wr * 64 + m * 16 + lhi * 4;
        #pragma unroll
        for (int n = 0; n < 4; ++n) {
            int ncol = col0 + wc * 64 + n * 16 + l16;
            float bv = bias[ncol];
            #pragma unroll
            for (int j = 0; j < 4; ++j) {
                float v = acc[m][n][j] + bv;
                int t = trow + j;
                if (MODE == 0) {
                    if (ncol < 768) {
                        int hh = ncol >> 6, d = ncol & 63;
                        Qb[((size_t)hh * TSEQ + t) * 64 + d] = f2bf(v * QSCALE);
                    } else if (ncol < 1536) {
                        int c = ncol - 768; int hh = c >> 6, d = c & 63;
                        Kb[((size_t)hh * TSEQ + t) * 64 + d] = f2bf(v);
                    } else {
                        int c = ncol - 1536; int hh = c >> 6, d = c & 63;
                        Vt[((size_t)hh * 64 + d) * TSEQ + t] = f2bf(v);
                    }
                } else {
                    Out[(size_t)t * N + ncol] = v;
                }
            }
        }
    }
}

// ---------------- flash attention (causal, swapped-operand, balanced) -------
// grid: 768 blocks = 64 complementary pairs x 12 heads; 512 threads = 8 waves.
// Each block runs TWO phases: qblk = 127-pair, then qblk = pair. Total tiles
// per block = (qa+qb)/2 + 2 ~ 66 -- uniform, so no drain. Per phase, the 8
// waves stripe the KV axis (kt = w, w+8, ...); private online-softmax state;
// two-round LDS merge (waves 4-7 -> slots, pairwise merge, waves 1-3 ->
// slots, wave 0 final). Defer-max (THR=8, log2 domain) skips most rescales.

__global__ __launch_bounds__(512, 5)
void attn_fwd(const unsigned short* __restrict__ Qb,
              const unsigned short* __restrict__ Kb,
              const unsigned short* __restrict__ Vt,
              unsigned short* __restrict__ Y)
{
    __shared__ __align__(16) float Osh[4][32][64];   // [slot][elem][lane]
    __shared__ float Msh[4][64];
    __shared__ float Lsh[4][64];

    const int tid  = threadIdx.x;
    const int lane = tid & 63;
    const int w    = tid >> 6;          // 0..7
    const int l31  = lane & 31;
    const int hi   = lane >> 5;
    const int bid  = blockIdx.x;
    const int h    = bid % NHEAD;
    const int pair = bid / NHEAD;       // 0..63

    const unsigned short* Qh = Qb + (size_t)h * TSEQ * 64;
    const unsigned short* Kh = Kb + (size_t)h * TSEQ * 64;
    const unsigned short* Vh = Vt + (size_t)h * 64 * TSEQ;

    #pragma unroll 1
    for (int phase = 0; phase < 2; ++phase) {
        const int qblk = phase ? pair : (127 - pair);
        const int q0   = qblk * 32;
        const int ntiles = q0 / 64 + 1;

        // Q^T B-fragments: Q[q0+l31][ks*16 + hi*8 + j] (Q pre-scaled)
        bf16x8 qf[4];
        #pragma unroll
        for (int ks = 0; ks < 4; ++ks)
            qf[ks] = *reinterpret_cast<const bf16x8*>(
                &Qh[(size_t)(q0 + l31) * 64 + ks * 16 + hi * 8]);

        f32x16 o0 = {}, o1 = {};
        float mrun = -1e30f, lrun = 0.f;

        for (int kt = w; kt < ntiles; kt += 8) {
            const int kv0 = kt * 64;

            // K fragments (B of S^T)
            bf16x8 kf[2][4];
            #pragma unroll
            for (int sub = 0; sub < 2; ++sub)
                #pragma unroll
                for (int ks = 0; ks < 4; ++ks)
                    kf[sub][ks] = *reinterpret_cast<const bf16x8*>(
                        &Kh[(size_t)(kv0 + sub * 32 + l31) * 64 + ks * 16 + hi * 8]);

            // V fragments (A of O^T) — issued early, consumed after softmax
            bf16x8 vf[2][4];
            #pragma unroll
            for (int d = 0; d < 2; ++d)
                #pragma unroll
                for (int ks = 0; ks < 4; ++ks)
                    vf[d][ks] = *reinterpret_cast<const bf16x8*>(
                        &Vh[(size_t)(d * 32 + l31) * TSEQ + kv0 + ks * 16 + hi * 8]);

            // S^T = K · Q^T  (rows = kv, cols = q)
            f32x16 s0 = {}, s1 = {};
            #pragma unroll
            for (int ks = 0; ks < 4; ++ks) {
                s0 = mfma32(kf[0][ks], qf[ks], s0);
                s1 = mfma32(kf[1][ks], qf[ks], s1);
            }

            float sv[32];
            #pragma unroll
            for (int i = 0; i < 16; ++i) { sv[i] = s0[i]; sv[16 + i] = s1[i]; }

            if (kt == ntiles - 1) {           // diagonal tile: causal mask
                const int qrel = q0 + l31 - kv0;
                const int h4 = hi * 4;
                #pragma unroll
                for (int i = 0; i < 32; ++i) {
                    int kvbase = (i >> 4) * 32 + (i & 3) + 8 * ((i >> 2) & 3);
                    if (kvbase + h4 > qrel) sv[i] = -1e30f;
                }
            }

            // row max: in-lane tree + cross-half swap
            float t[16];
            #pragma unroll
            for (int i = 0; i < 16; ++i) t[i] = fmaxf(sv[i], sv[i + 16]);
            #pragma unroll
            for (int s = 8; s >= 1; s >>= 1)
                #pragma unroll
                for (int i = 0; i < s; ++i) t[i] = fmaxf(t[i], t[i + s]);
            float pmax;
            {
                union { float f; unsigned u; } c; c.f = t[0];
                u32x2 r = __builtin_amdgcn_permlane32_swap(c.u, c.u, false, false);
                union { unsigned u; float f; } ra, rb; ra.u = r.x; rb.u = r.y;
                pmax = fmaxf(ra.f, rb.f);
            }

            // defer-max (T13): only rescale when row max grows past mrun + 8
            if (!__all(pmax <= mrun + 8.0f)) {
                float mnew = fmaxf(mrun, pmax);
                float corr = exp2f(mrun - mnew);
                #pragma unroll
                for (int i = 0; i < 16; ++i) { o0[i] *= corr; o1[i] *= corr; }
                lrun *= corr;
                mrun = mnew;
            }

            float e[32];
            #pragma unroll
            for (int i = 0; i < 32; ++i) e[i] = exp2f(sv[i] - mrun);

            // row sum: in-lane tree + cross-half swap
            float u[16];
            #pragma unroll
            for (int i = 0; i < 16; ++i) u[i] = e[i] + e[i + 16];
            #pragma unroll
            for (int s = 8; s >= 1; s >>= 1)
                #pragma unroll
                for (int i = 0; i < s; ++i) u[i] += u[i + s];
            float ps;
            {
                union { float f; unsigned u; } c; c.f = u[0];
                u32x2 r = __builtin_amdgcn_permlane32_swap(c.u, c.u, false, false);
                union { unsigned u; float f; } ra, rb; ra.u = r.x; rb.u = r.y;
                ps = ra.f + rb.f;
            }
            lrun += ps;

            // pack P^T B-fragments: per 16-kv step, 4 cvt_pk + 2 permlane
            bf16x8 pw[4];
            #pragma unroll
            for (int ks = 0; ks < 4; ++ks) {
                const int eb = (ks >> 1) * 16 + (ks & 1) * 8;
                u32x2 r02 = __builtin_amdgcn_permlane32_swap(
                    cvt_pk_bf16(e[eb + 0], e[eb + 1]), cvt_pk_bf16(e[eb + 4], e[eb + 5]),
                    false, false);
                u32x2 r13 = __builtin_amdgcn_permlane32_swap(
                    cvt_pk_bf16(e[eb + 2], e[eb + 3]), cvt_pk_bf16(e[eb + 6], e[eb + 7]),
                    false, false);
                union { unsigned wd[4]; bf16x8 v; } pk;
                pk.wd[0] = r02.x; pk.wd[1] = r13.x; pk.wd[2] = r02.y; pk.wd[3] = r13.y;
                pw[ks] = pk.v;
            }

            // O^T += V^T · P^T
            #pragma unroll
            for (int ks = 0; ks < 4; ++ks) {
                o0 = mfma32(vf[0][ks], pw[ks], o0);
                o1 = mfma32(vf[1][ks], pw[ks], o1);
            }
        }

        // ---- two-round merge: 8 partials -> 1 (4 LDS slots) ----
        __syncthreads();                       // slots free (prev phase done)
        if (w >= 4) {
            #pragma unroll
            for (int i = 0; i < 16; ++i) {
                Osh[w - 4][i][lane]      = o0[i];
                Osh[w - 4][16 + i][lane] = o1[i];
            }
            Msh[w - 4][lane] = mrun;
            Lsh[w - 4][lane] = lrun;
        }
        __syncthreads();
        if (w < 4) {
            float mp = Msh[w][lane], lp = Lsh[w][lane];
            float mn = fmaxf(mrun, mp);
            float a = exp2f(mrun - mn), b = exp2f(mp - mn);
            #pragma unroll
            for (int i = 0; i < 16; ++i) {
                o0[i] = o0[i] * a + Osh[w][i][lane] * b;
                o1[i] = o1[i] * a + Osh[w][16 + i][lane] * b;
            }
            lrun = lrun * a + lp * b;
            mrun = mn;
        }
        __syncthreads();
        if (w >= 1 && w < 4) {
            #pragma unroll
            for (int i = 0; i < 16; ++i) {
                Osh[w - 1][i][lane]      = o0[i];
                Osh[w - 1][16 + i][lane] = o1[i];
            }
            Msh[w - 1][lane] = mrun;
            Lsh[w - 1][lane] = lrun;
        }
        __syncthreads();
        if (w == 0) {
            #pragma unroll
            for (int p = 0; p < 3; ++p) {
                float mp = Msh[p][lane], lp = Lsh[p][lane];
                float mn = fmaxf(mrun, mp);
                float a = exp2f(mrun - mn), b = exp2f(mp - mn);
                #pragma unroll
                for (int i = 0; i < 16; ++i) {
                    o0[i] = o0[i] * a + Osh[p][i][lane] * b;
                    o1[i] = o1[i] * a + Osh[p][16 + i][lane] * b;
                }
                lrun = lrun * a + lp * b;
                mrun = mn;
            }

            // epilogue: y[t][h*64 + d], d = dsub*32 + (rr&3) + 8*(rr>>2) + 4*hi
            float inv = 1.0f / lrun;
            const int trow = q0 + l31;
            #pragma unroll
            for (int d = 0; d < 2; ++d) {
                #pragma unroll
                for (int p = 0; p < 8; ++p) {
                    const int rr = p * 2;
                    float v0 = (d ? o1 : o0)[rr] * inv;
                    float v1 = (d ? o1 : o0)[rr + 1] * inv;
                    int c = h * 64 + d * 32 + (rr & 3) + 8 * (rr >> 2) + hi * 4;
                    unsigned wd = cvt_pk_bf16(v0, v1);
                    *reinterpret_cast<unsigned*>(
                        const_cast<unsigned short*>(&Y[(size_t)trow * CDIM + c])) = wd;
                }
            }
        }
    }
}

// ---------------- launch ----------------

extern "C" void kernel_launch(void* const* d_in, const int* in_sizes, int n_in,
                              void* d_out, int out_size, void* d_ws, size_t ws_size,
                              hipStream_t stream) {
    const float* x      = (const float*)d_in[0];
    const float* w_attn = (const float*)d_in[1];
    const float* b_attn = (const float*)d_in[2];
    const float* w_proj = (const float*)d_in[3];
    const float* b_proj = (const float*)d_in[4];
    float* out = (float*)d_out;

    char* ws = (char*)d_ws;
    unsigned short* xb  = (unsigned short*)(ws + 0);         // 4096*768
    unsigned short* WaT = (unsigned short*)(ws + 6291456);   // 2304*768
    unsigned short* WpT = (unsigned short*)(ws + 9830400);   // 768*768
    unsigned short* Qb  = (unsigned short*)(ws + 11010048);  // 12*4096*64
    unsigned short* Kb  = (unsigned short*)(ws + 17301504);  // 12*4096*64
    unsigned short* Vt  = (unsigned short*)(ws + 23592960);  // 12*64*4096
    unsigned short* Yb  = (unsigned short*)(ws + 29884416);  // 4096*768

    cvt_f32_bf16<<<2048, 256, 0, stream>>>(x, xb, TSEQ * CDIM / 4);
    transpose_cvt<<<dim3(2304 / 32, 768 / 32), 256, 0, stream>>>(w_attn, WaT, 768, 2304);
    transpose_cvt<<<dim3(768 / 32, 768 / 32), 256, 0, stream>>>(w_proj, WpT, 768, 768);

    gemm_bt<0><<<dim3(TSEQ / 128, 2304 / 128), 256, 0, stream>>>(
        xb, WaT, b_attn, Qb, Kb, Vt, nullptr, TSEQ, 2304, CDIM);

    attn_fwd<<<NHEAD * 64, 512, 0, stream>>>(Qb, Kb, Vt, Yb);

    gemm_bt<1><<<dim3(TSEQ / 128, CDIM / 128), 256, 0, stream>>>(
        Yb, WpT, b_proj, nullptr, nullptr, nullptr, out, TSEQ, CDIM, CDIM);
}

// Round 7
// 271.082 us; speedup vs baseline: 1.2938x; 1.2938x over previous
//
#include <hip/hip_runtime.h>
#include <hip/hip_bf16.h>
#include <cstdint>
#include <cstddef>

#define NHEAD 12
#define TSEQ  4096
#define CDIM  768

typedef __attribute__((ext_vector_type(8))) short bf16x8;
typedef __attribute__((ext_vector_type(4))) float f32x4;
typedef __attribute__((ext_vector_type(16))) float f32x16;
typedef __attribute__((ext_vector_type(2))) unsigned int u32x2;

typedef __attribute__((address_space(1))) void gvoid;
typedef __attribute__((address_space(3))) void lvoid;

#define QSCALE 0.1803368801111204f   /* 0.125 * log2(e) */

static __device__ __forceinline__ unsigned short f2bf(float f) {
    union { float f; uint32_t u; } v; v.f = f;
    uint32_t u = v.u;
    u += 0x7fffu + ((u >> 16) & 1u);   // RNE
    return (unsigned short)(u >> 16);
}
static __device__ __forceinline__ float bf2f(unsigned short u) {
    union { uint32_t u; float f; } v; v.u = ((uint32_t)u) << 16;
    return v.f;
}

static __device__ __forceinline__ f32x4 mfma16(bf16x8 a, bf16x8 b, f32x4 c) {
    return __builtin_amdgcn_mfma_f32_16x16x32_bf16(a, b, c, 0, 0, 0);
}
static __device__ __forceinline__ f32x16 mfma32(bf16x8 a, bf16x8 b, f32x16 c) {
    return __builtin_amdgcn_mfma_f32_32x32x16_bf16(a, b, c, 0, 0, 0);
}
static __device__ __forceinline__ unsigned cvt_pk_bf16(float lo, float hi) {
    unsigned r;
    asm("v_cvt_pk_bf16_f32 %0, %1, %2" : "=v"(r) : "v"(lo), "v"(hi));
    return r;
}

// ---------------- conversion kernels ----------------

__global__ void cvt_f32_bf16(const float* __restrict__ in, unsigned short* __restrict__ out, int n4) {
    int i = blockIdx.x * blockDim.x + threadIdx.x;
    int stride = gridDim.x * blockDim.x;
    for (int idx = i; idx < n4; idx += stride) {
        float4 v = reinterpret_cast<const float4*>(in)[idx];
        ushort4 o;
        o.x = f2bf(v.x); o.y = f2bf(v.y); o.z = f2bf(v.z); o.w = f2bf(v.w);
        reinterpret_cast<ushort4*>(out)[idx] = o;
    }
}

// W [K][N] f32  ->  Wt [N][K] bf16
__global__ void transpose_cvt(const float* __restrict__ W, unsigned short* __restrict__ Wt,
                              int K, int N) {
    __shared__ float tile[32][33];
    int n0 = blockIdx.x * 32;
    int k0 = blockIdx.y * 32;
    int tx = threadIdx.x & 31;
    int ty = threadIdx.x >> 5;   // 0..7
    #pragma unroll
    for (int r = ty; r < 32; r += 8)
        tile[r][tx] = W[(size_t)(k0 + r) * N + n0 + tx];
    __syncthreads();
    #pragma unroll
    for (int r = ty; r < 32; r += 8)
        Wt[(size_t)(n0 + r) * K + k0 + tx] = f2bf(tile[tx][r]);
}

// ---------------- GEMM core (A [M][K] bf16, Bt [N][K] bf16) ----------------
// MODE 0: qkv epilogue -> Q[h][t][d] (pre-scaled), K[h][t][d], Vt[h][d][t]
// MODE 1: proj epilogue -> Out f32 [M][N] (+bias)

template<int MODE>
__global__ __launch_bounds__(256)
void gemm_bt(const unsigned short* __restrict__ A,
             const unsigned short* __restrict__ Bt,
             const float* __restrict__ bias,
             unsigned short* __restrict__ Qb,
             unsigned short* __restrict__ Kb,
             unsigned short* __restrict__ Vt,
             float* __restrict__ Out,
             int M, int N, int K)
{
    __shared__ __align__(16) unsigned short As[128 * 32];
    __shared__ __align__(16) unsigned short Bs[128 * 32];

    const int tid  = threadIdx.x;
    const int lane = tid & 63;
    const int w    = tid >> 6;       // 4 waves
    const int wr   = w >> 1, wc = w & 1;
    const int row0 = blockIdx.x * 128;
    const int col0 = blockIdx.y * 128;
    const int l16  = lane & 15;
    const int lhi  = lane >> 4;

    f32x4 acc[4][4] = {};

    for (int k0 = 0; k0 < K; k0 += 32) {
        __syncthreads();
        #pragma unroll
        for (int r = 0; r < 2; ++r) {
            int b    = r * 4096 + w * 1024 + lane * 16;
            int trow = b >> 6;
            int koff = b & 63;
            const char* gA = (const char*)A  + ((size_t)(row0 + trow) * K + k0) * 2 + koff;
            const char* gB = (const char*)Bt + ((size_t)(col0 + trow) * K + k0) * 2 + koff;
            __builtin_amdgcn_global_load_lds((gvoid*)gA,
                (lvoid*)((char*)As + r * 4096 + w * 1024), 16, 0, 0);
            __builtin_amdgcn_global_load_lds((gvoid*)gB,
                (lvoid*)((char*)Bs + r * 4096 + w * 1024), 16, 0, 0);
        }
        __syncthreads();

        bf16x8 a[4], bfr[4];
        #pragma unroll
        for (int m = 0; m < 4; ++m) {
            int row = wr * 64 + m * 16 + l16;
            a[m] = *reinterpret_cast<const bf16x8*>(&As[row * 32 + lhi * 8]);
        }
        #pragma unroll
        for (int n = 0; n < 4; ++n) {
            int col = wc * 64 + n * 16 + l16;
            bfr[n] = *reinterpret_cast<const bf16x8*>(&Bs[col * 32 + lhi * 8]);
        }
        #pragma unroll
        for (int m = 0; m < 4; ++m)
            #pragma unroll
            for (int n = 0; n < 4; ++n)
                acc[m][n] = mfma16(a[m], bfr[n], acc[m][n]);
    }

    #pragma unroll
    for (int m = 0; m < 4; ++m) {
        int trow = row0 + wr * 64 + m * 16 + lhi * 4;
        #pragma unroll
        for (int n = 0; n < 4; ++n) {
            int ncol = col0 + wc * 64 + n * 16 + l16;
            float bv = bias[ncol];
            #pragma unroll
            for (int j = 0; j < 4; ++j) {
                float v = acc[m][n][j] + bv;
                int t = trow + j;
                if (MODE == 0) {
                    if (ncol < 768) {
                        int hh = ncol >> 6, d = ncol & 63;
                        Qb[((size_t)hh * TSEQ + t) * 64 + d] = f2bf(v * QSCALE);
                    } else if (ncol < 1536) {
                        int c = ncol - 768; int hh = c >> 6, d = c & 63;
                        Kb[((size_t)hh * TSEQ + t) * 64 + d] = f2bf(v);
                    } else {
                        int c = ncol - 1536; int hh = c >> 6, d = c & 63;
                        Vt[((size_t)hh * 64 + d) * TSEQ + t] = f2bf(v);
                    }
                } else {
                    Out[(size_t)t * N + ncol] = v;
                }
            }
        }
    }
}

// ---------------- flash attention (causal, swapped-operand, balanced) -------
// grid: NHEAD*64*NSPLIT blocks of 256 thr (4 waves). Block (h, pair, s) runs
// two phases: qblk = 127-pair, then qblk = pair (uniform total work). Within
// a phase the KV axis is striped 4*NSPLIT ways: wave w of sub-block s takes
// kt = w*NSPLIT + s (+ 4*NSPLIT*i). Private online softmax per wave
// (defer-max THR=8, log2 domain); in-block 4->1 LDS merge; wave 0 then
// writes either Y (NSPLIT==1) or an (m,l,O-bf16) partial (NSPLIT==2) that
// attn_merge combines. launch_bounds(256,3) = R4's proven 84-VGPR config.

template<int NSPLIT>
__global__ __launch_bounds__(256, 3)
void attn_fwd(const unsigned short* __restrict__ Qb,
              const unsigned short* __restrict__ Kb,
              const unsigned short* __restrict__ Vt,
              unsigned short* __restrict__ Y,
              unsigned short* __restrict__ PO,
              float* __restrict__ PM,
              float* __restrict__ PL)
{
    __shared__ __align__(16) float Osh[3][32][64];   // [slot][elem][lane]
    __shared__ float Msh[3][64];
    __shared__ float Lsh[3][64];

    const int tid  = threadIdx.x;
    const int lane = tid & 63;
    const int w    = tid >> 6;
    const int l31  = lane & 31;
    const int hi   = lane >> 5;
    const int bid  = blockIdx.x;
    const int h    = bid % NHEAD;
    const int rest = bid / NHEAD;
    const int pair = rest % 64;
    const int s    = rest / 64;          // 0..NSPLIT-1

    const unsigned short* Qh = Qb + (size_t)h * TSEQ * 64;
    const unsigned short* Kh = Kb + (size_t)h * TSEQ * 64;
    const unsigned short* Vh = Vt + (size_t)h * 64 * TSEQ;

    #pragma unroll 1
    for (int phase = 0; phase < 2; ++phase) {
        const int qblk = phase ? pair : (127 - pair);
        const int q0   = qblk * 32;
        const int ntiles = q0 / 64 + 1;

        // Q^T B-fragments: Q[q0+l31][ks*16 + hi*8 + j] (Q pre-scaled)
        bf16x8 qf[4];
        #pragma unroll
        for (int ks = 0; ks < 4; ++ks)
            qf[ks] = *reinterpret_cast<const bf16x8*>(
                &Qh[(size_t)(q0 + l31) * 64 + ks * 16 + hi * 8]);

        f32x16 o0 = {}, o1 = {};
        float mrun = -1e30f, lrun = 0.f;

        for (int kt = w * NSPLIT + s; kt < ntiles; kt += 4 * NSPLIT) {
            const int kv0 = kt * 64;

            // K fragments (B of S^T)
            bf16x8 kf[2][4];
            #pragma unroll
            for (int sub = 0; sub < 2; ++sub)
                #pragma unroll
                for (int ks = 0; ks < 4; ++ks)
                    kf[sub][ks] = *reinterpret_cast<const bf16x8*>(
                        &Kh[(size_t)(kv0 + sub * 32 + l31) * 64 + ks * 16 + hi * 8]);

            // V fragments (A of O^T) — issued early, consumed after softmax
            bf16x8 vf[2][4];
            #pragma unroll
            for (int d = 0; d < 2; ++d)
                #pragma unroll
                for (int ks = 0; ks < 4; ++ks)
                    vf[d][ks] = *reinterpret_cast<const bf16x8*>(
                        &Vh[(size_t)(d * 32 + l31) * TSEQ + kv0 + ks * 16 + hi * 8]);

            // S^T = K · Q^T  (rows = kv, cols = q)
            f32x16 s0 = {}, s1 = {};
            #pragma unroll
            for (int ks = 0; ks < 4; ++ks) {
                s0 = mfma32(kf[0][ks], qf[ks], s0);
                s1 = mfma32(kf[1][ks], qf[ks], s1);
            }

            float sv[32];
            #pragma unroll
            for (int i = 0; i < 16; ++i) { sv[i] = s0[i]; sv[16 + i] = s1[i]; }

            if (kt == ntiles - 1) {           // diagonal tile: causal mask
                const int qrel = q0 + l31 - kv0;
                const int h4 = hi * 4;
                #pragma unroll
                for (int i = 0; i < 32; ++i) {
                    int kvbase = (i >> 4) * 32 + (i & 3) + 8 * ((i >> 2) & 3);
                    if (kvbase + h4 > qrel) sv[i] = -1e30f;
                }
            }

            // row max: in-lane tree + cross-half swap
            float t[16];
            #pragma unroll
            for (int i = 0; i < 16; ++i) t[i] = fmaxf(sv[i], sv[i + 16]);
            #pragma unroll
            for (int ss = 8; ss >= 1; ss >>= 1)
                #pragma unroll
                for (int i = 0; i < ss; ++i) t[i] = fmaxf(t[i], t[i + ss]);
            float pmax;
            {
                union { float f; unsigned u; } c; c.f = t[0];
                u32x2 r = __builtin_amdgcn_permlane32_swap(c.u, c.u, false, false);
                union { unsigned u; float f; } ra, rb; ra.u = r.x; rb.u = r.y;
                pmax = fmaxf(ra.f, rb.f);
            }

            // defer-max (T13): only rescale when row max grows past mrun + 8
            if (!__all(pmax <= mrun + 8.0f)) {
                float mnew = fmaxf(mrun, pmax);
                float corr = exp2f(mrun - mnew);
                #pragma unroll
                for (int i = 0; i < 16; ++i) { o0[i] *= corr; o1[i] *= corr; }
                lrun *= corr;
                mrun = mnew;
            }

            float e[32];
            #pragma unroll
            for (int i = 0; i < 32; ++i) e[i] = exp2f(sv[i] - mrun);

            // row sum: in-lane tree + cross-half swap
            float u[16];
            #pragma unroll
            for (int i = 0; i < 16; ++i) u[i] = e[i] + e[i + 16];
            #pragma unroll
            for (int ss = 8; ss >= 1; ss >>= 1)
                #pragma unroll
                for (int i = 0; i < ss; ++i) u[i] += u[i + ss];
            float ps;
            {
                union { float f; unsigned u; } c; c.f = u[0];
                u32x2 r = __builtin_amdgcn_permlane32_swap(c.u, c.u, false, false);
                union { unsigned u; float f; } ra, rb; ra.u = r.x; rb.u = r.y;
                ps = ra.f + rb.f;
            }
            lrun += ps;

            // pack P^T B-fragments: per 16-kv step, 4 cvt_pk + 2 permlane
            bf16x8 pw[4];
            #pragma unroll
            for (int ks = 0; ks < 4; ++ks) {
                const int eb = (ks >> 1) * 16 + (ks & 1) * 8;
                u32x2 r02 = __builtin_amdgcn_permlane32_swap(
                    cvt_pk_bf16(e[eb + 0], e[eb + 1]), cvt_pk_bf16(e[eb + 4], e[eb + 5]),
                    false, false);
                u32x2 r13 = __builtin_amdgcn_permlane32_swap(
                    cvt_pk_bf16(e[eb + 2], e[eb + 3]), cvt_pk_bf16(e[eb + 6], e[eb + 7]),
                    false, false);
                union { unsigned wd[4]; bf16x8 v; } pk;
                pk.wd[0] = r02.x; pk.wd[1] = r13.x; pk.wd[2] = r02.y; pk.wd[3] = r13.y;
                pw[ks] = pk.v;
            }

            // O^T += V^T · P^T
            #pragma unroll
            for (int ks = 0; ks < 4; ++ks) {
                o0 = mfma32(vf[0][ks], pw[ks], o0);
                o1 = mfma32(vf[1][ks], pw[ks], o1);
            }
        }

        // ---- in-block 4->1 merge (waves 1-3 dump, wave 0 combines) ----
        __syncthreads();                 // slots free (prev phase merge done)
        if (w > 0) {
            #pragma unroll
            for (int i = 0; i < 16; ++i) {
                Osh[w - 1][i][lane]      = o0[i];
                Osh[w - 1][16 + i][lane] = o1[i];
            }
            Msh[w - 1][lane] = mrun;
            Lsh[w - 1][lane] = lrun;
        }
        __syncthreads();
        if (w == 0) {
            #pragma unroll
            for (int p = 0; p < 3; ++p) {
                float mp = Msh[p][lane], lp = Lsh[p][lane];
                float mn = fmaxf(mrun, mp);
                float a = exp2f(mrun - mn), b = exp2f(mp - mn);
                #pragma unroll
                for (int i = 0; i < 16; ++i) {
                    o0[i] = o0[i] * a + Osh[p][i][lane] * b;
                    o1[i] = o1[i] * a + Osh[p][16 + i][lane] * b;
                }
                lrun = lrun * a + lp * b;
                mrun = mn;
            }

            if constexpr (NSPLIT == 1) {
                // epilogue: y[t][h*64+d], d = dsub*32 + (rr&3)+8*(rr>>2)+4*hi
                float inv = 1.0f / lrun;
                const int trow = q0 + l31;
                #pragma unroll
                for (int d = 0; d < 2; ++d) {
                    #pragma unroll
                    for (int p = 0; p < 8; ++p) {
                        const int rr = p * 2;
                        float v0 = (d ? o1 : o0)[rr] * inv;
                        float v1 = (d ? o1 : o0)[rr + 1] * inv;
                        int c = h * 64 + d * 32 + (rr & 3) + 8 * (rr >> 2) + hi * 4;
                        unsigned wd = cvt_pk_bf16(v0, v1);
                        *reinterpret_cast<unsigned*>(
                            const_cast<unsigned short*>(&Y[(size_t)trow * CDIM + c])) = wd;
                    }
                }
            } else {
                // dump partial: PO[u2][e 0..31][lane], PM/PL[u2][q 0..31]
                const int u2 = (h * 128 + qblk) * NSPLIT + s;
                unsigned short* po = PO + (size_t)u2 * 2048;
                #pragma unroll
                for (int i = 0; i < 16; ++i) {
                    po[i * 64 + lane]        = f2bf(o0[i]);
                    po[(16 + i) * 64 + lane] = f2bf(o1[i]);
                }
                if (lane < 32) {
                    PM[(size_t)u2 * 32 + lane] = mrun;
                    PL[(size_t)u2 * 32 + lane] = lrun;
                }
            }
        }
    }
}

// ---------------- partial merge: 2 partials per (h, qblk) -> Y -------------
// grid: 1536 blocks (one per unit), 256 thr. Thread handles (r, d-pair):
// coalesced dword writes into Y.

__global__ __launch_bounds__(256)
void attn_merge(const unsigned short* __restrict__ PO,
                const float* __restrict__ PM,
                const float* __restrict__ PL,
                unsigned short* __restrict__ Y)
{
    const int unit = blockIdx.x;        // h*128 + q
    const int h = unit >> 7, q = unit & 127;
    const unsigned short* p0 = PO + (size_t)unit * 2 * 2048;
    const unsigned short* p1 = p0 + 2048;
    const float* m01 = PM + (size_t)unit * 2 * 32;
    const float* l01 = PL + (size_t)unit * 2 * 32;

    #pragma unroll
    for (int i = 0; i < 4; ++i) {
        int idx = threadIdx.x + i * 256;     // 0..1023
        int r  = idx >> 5;                   // q-row 0..31
        int d0 = (idx & 31) * 2;             // even d

        float m0 = m01[r], m1 = m01[32 + r];
        float l0 = l01[r], l1 = l01[32 + r];
        float mM = fmaxf(m0, m1);
        float a = exp2f(m0 - mM), b = exp2f(m1 - mM);
        float inv = 1.0f / (l0 * a + l1 * b);

        // d -> (e, lane): d5=d&31: i_e = (d5&3)|(((d5>>3)&3)<<2); hi=(d5>>2)&1
        int d5 = d0 & 31;
        int ie = (d5 & 3) | (((d5 >> 3) & 3) << 2);
        int hie = (d5 >> 2) & 1;
        int e0 = ie + ((d0 >> 5) << 4);      // d1 = d0+1 -> e0+1, same lane
        int ln = r + 32 * hie;

        float v0 = (bf2f(p0[e0 * 64 + ln]) * a + bf2f(p1[e0 * 64 + ln]) * b) * inv;
        float v1 = (bf2f(p0[(e0 + 1) * 64 + ln]) * a + bf2f(p1[(e0 + 1) * 64 + ln]) * b) * inv;

        unsigned wd = cvt_pk_bf16(v0, v1);
        *reinterpret_cast<unsigned*>(&Y[(size_t)(q * 32 + r) * CDIM + h * 64 + d0]) = wd;
    }
}

// ---------------- launch ----------------

extern "C" void kernel_launch(void* const* d_in, const int* in_sizes, int n_in,
                              void* d_out, int out_size, void* d_ws, size_t ws_size,
                              hipStream_t stream) {
    const float* x      = (const float*)d_in[0];
    const float* w_attn = (const float*)d_in[1];
    const float* b_attn = (const float*)d_in[2];
    const float* w_proj = (const float*)d_in[3];
    const float* b_proj = (const float*)d_in[4];
    float* out = (float*)d_out;

    char* ws = (char*)d_ws;
    unsigned short* xb  = (unsigned short*)(ws + 0);         // 4096*768
    unsigned short* WaT = (unsigned short*)(ws + 6291456);   // 2304*768
    unsigned short* WpT = (unsigned short*)(ws + 9830400);   // 768*768
    unsigned short* Qb  = (unsigned short*)(ws + 11010048);  // 12*4096*64
    unsigned short* Kb  = (unsigned short*)(ws + 17301504);  // 12*4096*64
    unsigned short* Vt  = (unsigned short*)(ws + 23592960);  // 12*64*4096
    unsigned short* Yb  = (unsigned short*)(ws + 29884416);  // 4096*768

    // partial buffers (after Yb): PO 3072*4KB bf16, PM/PL 3072*128B f32
    const size_t poOff = 36175872;
    unsigned short* PO = (unsigned short*)(ws + poOff);
    float* PM = (float*)(ws + poOff + 12582912);
    float* PL = (float*)(ws + poOff + 12582912 + 393216);
    const bool split2 = ws_size >= poOff + 12582912 + 2 * 393216;

    cvt_f32_bf16<<<2048, 256, 0, stream>>>(x, xb, TSEQ * CDIM / 4);
    transpose_cvt<<<dim3(2304 / 32, 768 / 32), 256, 0, stream>>>(w_attn, WaT, 768, 2304);
    transpose_cvt<<<dim3(768 / 32, 768 / 32), 256, 0, stream>>>(w_proj, WpT, 768, 768);

    gemm_bt<0><<<dim3(TSEQ / 128, 2304 / 128), 256, 0, stream>>>(
        xb, WaT, b_attn, Qb, Kb, Vt, nullptr, TSEQ, 2304, CDIM);

    if (split2) {
        attn_fwd<2><<<NHEAD * 64 * 2, 256, 0, stream>>>(Qb, Kb, Vt, Yb, PO, PM, PL);
        attn_merge<<<NHEAD * 128, 256, 0, stream>>>(PO, PM, PL, Yb);
    } else {
        attn_fwd<1><<<NHEAD * 64, 256, 0, stream>>>(Qb, Kb, Vt, Yb, PO, PM, PL);
    }

    gemm_bt<1><<<dim3(TSEQ / 128, CDIM / 128), 256, 0, stream>>>(
        Yb, WpT, b_proj, nullptr, nullptr, nullptr, out, TSEQ, CDIM, CDIM);
}

// Round 9
// 243.048 us; speedup vs baseline: 1.4431x; 1.1153x over previous
//
#include <hip/hip_runtime.h>
#include <hip/hip_bf16.h>
#include <cstdint>
#include <cstddef>

#define NHEAD 12
#define TSEQ  4096
#define CDIM  768

typedef __attribute__((ext_vector_type(8))) short bf16x8;
typedef __attribute__((ext_vector_type(4))) float f32x4;
typedef __attribute__((ext_vector_type(16))) float f32x16;
typedef __attribute__((ext_vector_type(2))) unsigned int u32x2;

typedef __attribute__((address_space(1))) void gvoid;
typedef __attribute__((address_space(3))) void lvoid;

#define QSCALE 0.1803368801111204f   /* 0.125 * log2(e) */

static __device__ __forceinline__ unsigned short f2bf(float f) {
    union { float f; uint32_t u; } v; v.f = f;
    uint32_t u = v.u;
    u += 0x7fffu + ((u >> 16) & 1u);   // RNE
    return (unsigned short)(u >> 16);
}

static __device__ __forceinline__ f32x4 mfma16(bf16x8 a, bf16x8 b, f32x4 c) {
    return __builtin_amdgcn_mfma_f32_16x16x32_bf16(a, b, c, 0, 0, 0);
}
static __device__ __forceinline__ f32x16 mfma32(bf16x8 a, bf16x8 b, f32x16 c) {
    return __builtin_amdgcn_mfma_f32_32x32x16_bf16(a, b, c, 0, 0, 0);
}
static __device__ __forceinline__ unsigned cvt_pk_bf16(float lo, float hi) {
    unsigned r;
    asm("v_cvt_pk_bf16_f32 %0, %1, %2" : "=v"(r) : "v"(lo), "v"(hi));
    return r;
}

// ---------------- conversion kernels ----------------

__global__ void cvt_f32_bf16(const float* __restrict__ in, unsigned short* __restrict__ out, int n4) {
    int i = blockIdx.x * blockDim.x + threadIdx.x;
    int stride = gridDim.x * blockDim.x;
    for (int idx = i; idx < n4; idx += stride) {
        float4 v = reinterpret_cast<const float4*>(in)[idx];
        ushort4 o;
        o.x = f2bf(v.x); o.y = f2bf(v.y); o.z = f2bf(v.z); o.w = f2bf(v.w);
        reinterpret_cast<ushort4*>(out)[idx] = o;
    }
}

// W [K][N] f32  ->  Wt [N][K] bf16
__global__ void transpose_cvt(const float* __restrict__ W, unsigned short* __restrict__ Wt,
                              int K, int N) {
    __shared__ float tile[32][33];
    int n0 = blockIdx.x * 32;
    int k0 = blockIdx.y * 32;
    int tx = threadIdx.x & 31;
    int ty = threadIdx.x >> 5;   // 0..7
    #pragma unroll
    for (int r = ty; r < 32; r += 8)
        tile[r][tx] = W[(size_t)(k0 + r) * N + n0 + tx];
    __syncthreads();
    #pragma unroll
    for (int r = ty; r < 32; r += 8)
        Wt[(size_t)(n0 + r) * K + k0 + tx] = f2bf(tile[tx][r]);
}

// ---------------- GEMM core (A [M][K] bf16, Bt [N][K] bf16) ----------------
// MODE 0: QK epilogue -> Q[h][t][d] (pre-scaled), K[h][t][d]  (cols 0..1535)
// MODE 1: proj epilogue -> Out f32 [M][N] (+bias)
// MODE 2: V epilogue, SWAPPED mfma operands (C transposed for free) ->
//         Vt[c][t] rows, 16-lane-contiguous stores. Bt/bias pre-offset to V.

template<int MODE>
__global__ __launch_bounds__(256)
void gemm_bt(const unsigned short* __restrict__ A,
             const unsigned short* __restrict__ Bt,
             const float* __restrict__ bias,
             unsigned short* __restrict__ Qb,
             unsigned short* __restrict__ Kb,
             unsigned short* __restrict__ Vt,
             float* __restrict__ Out,
             int M, int N, int K)
{
    __shared__ __align__(16) unsigned short As[128 * 32];
    __shared__ __align__(16) unsigned short Bs[128 * 32];

    const int tid  = threadIdx.x;
    const int lane = tid & 63;
    const int w    = tid >> 6;       // 4 waves
    const int wr   = w >> 1, wc = w & 1;
    const int row0 = blockIdx.x * 128;
    const int col0 = blockIdx.y * 128;
    const int l16  = lane & 15;
    const int lhi  = lane >> 4;

    f32x4 acc[4][4] = {};

    for (int k0 = 0; k0 < K; k0 += 32) {
        __syncthreads();
        #pragma unroll
        for (int r = 0; r < 2; ++r) {
            int b    = r * 4096 + w * 1024 + lane * 16;
            int trow = b >> 6;
            int koff = b & 63;
            const char* gA = (const char*)A  + ((size_t)(row0 + trow) * K + k0) * 2 + koff;
            const char* gB = (const char*)Bt + ((size_t)(col0 + trow) * K + k0) * 2 + koff;
            __builtin_amdgcn_global_load_lds((gvoid*)gA,
                (lvoid*)((char*)As + r * 4096 + w * 1024), 16, 0, 0);
            __builtin_amdgcn_global_load_lds((gvoid*)gB,
                (lvoid*)((char*)Bs + r * 4096 + w * 1024), 16, 0, 0);
        }
        __syncthreads();

        bf16x8 a[4], bfr[4];
        #pragma unroll
        for (int m = 0; m < 4; ++m) {
            int row = wr * 64 + m * 16 + l16;
            a[m] = *reinterpret_cast<const bf16x8*>(&As[row * 32 + lhi * 8]);
        }
        #pragma unroll
        for (int n = 0; n < 4; ++n) {
            int col = wc * 64 + n * 16 + l16;
            bfr[n] = *reinterpret_cast<const bf16x8*>(&Bs[col * 32 + lhi * 8]);
        }
        #pragma unroll
        for (int m = 0; m < 4; ++m)
            #pragma unroll
            for (int n = 0; n < 4; ++n) {
                if constexpr (MODE == 2)
                    acc[m][n] = mfma16(bfr[n], a[m], acc[m][n]);   // C transposed
                else
                    acc[m][n] = mfma16(a[m], bfr[n], acc[m][n]);
            }
    }

    if constexpr (MODE == 2) {
        // C^T: col(lane&15) = t fragment of a[m]; row(lhi*4+j) = weight col c
        #pragma unroll
        for (int m = 0; m < 4; ++m) {
            int t = row0 + wr * 64 + m * 16 + l16;
            #pragma unroll
            for (int n = 0; n < 4; ++n) {
                int cb = col0 + wc * 64 + n * 16 + lhi * 4;
                #pragma unroll
                for (int j = 0; j < 4; ++j) {
                    int c = cb + j;                       // 0..767 (V channel)
                    float v = acc[m][n][j] + bias[c];
                    Vt[(size_t)c * TSEQ + t] = f2bf(v);   // 16 lanes: 32B run
                }
            }
        }
    } else {
        #pragma unroll
        for (int m = 0; m < 4; ++m) {
            int trow = row0 + wr * 64 + m * 16 + lhi * 4;
            #pragma unroll
            for (int n = 0; n < 4; ++n) {
                int ncol = col0 + wc * 64 + n * 16 + l16;
                float bv = bias[ncol];
                #pragma unroll
                for (int j = 0; j < 4; ++j) {
                    float v = acc[m][n][j] + bv;
                    int t = trow + j;
                    if (MODE == 0) {
                        if (ncol < 768) {
                            int hh = ncol >> 6, d = ncol & 63;
                            Qb[((size_t)hh * TSEQ + t) * 64 + d] = f2bf(v * QSCALE);
                        } else {
                            int c = ncol - 768; int hh = c >> 6, d = c & 63;
                            Kb[((size_t)hh * TSEQ + t) * 64 + d] = f2bf(v);
                        }
                    } else {
                        Out[(size_t)t * N + ncol] = v;
                    }
                }
            }
        }
    }
}

// ---------------- flash attention (causal, swapped-operand, paired) --------
// grid: 768 uniform blocks = 64 pairs x 12 heads; 256 thr = 4 waves. Block
// runs two phases: qblk = 127-pair then qblk = pair (total work constant ->
// all blocks finish together, no drain; 3 blocks/CU resident, single round).
// Within a phase, waves stripe the KV axis (kt = w, w+4, ...); private
// online softmax (defer-max THR=8, log2 domain); in-block 4->1 LDS merge;
// wave 0 writes Y. launch_bounds(256,3) = proven 84-VGPR no-spill config.

__global__ __launch_bounds__(256, 3)
void attn_fwd(const unsigned short* __restrict__ Qb,
              const unsigned short* __restrict__ Kb,
              const unsigned short* __restrict__ Vt,
              unsigned short* __restrict__ Y)
{
    __shared__ __align__(16) float Osh[3][32][64];   // [slot][elem][lane]
    __shared__ float Msh[3][64];
    __shared__ float Lsh[3][64];

    const int tid  = threadIdx.x;
    const int lane = tid & 63;
    const int w    = tid >> 6;
    const int l31  = lane & 31;
    const int hi   = lane >> 5;
    const int bid  = blockIdx.x;
    const int h    = bid % NHEAD;
    const int pair = bid / NHEAD;       // 0..63

    const unsigned short* Qh = Qb + (size_t)h * TSEQ * 64;
    const unsigned short* Kh = Kb + (size_t)h * TSEQ * 64;
    const unsigned short* Vh = Vt + (size_t)h * 64 * TSEQ;

    #pragma unroll 1
    for (int phase = 0; phase < 2; ++phase) {
        const int qblk = phase ? pair : (127 - pair);
        const int q0   = qblk * 32;
        const int ntiles = q0 / 64 + 1;

        // Q^T B-fragments: Q[q0+l31][ks*16 + hi*8 + j] (Q pre-scaled)
        bf16x8 qf[4];
        #pragma unroll
        for (int ks = 0; ks < 4; ++ks)
            qf[ks] = *reinterpret_cast<const bf16x8*>(
                &Qh[(size_t)(q0 + l31) * 64 + ks * 16 + hi * 8]);

        f32x16 o0 = {}, o1 = {};
        float mrun = -1e30f, lrun = 0.f;

        for (int kt = w; kt < ntiles; kt += 4) {
            const int kv0 = kt * 64;

            // K fragments (B of S^T)
            bf16x8 kf[2][4];
            #pragma unroll
            for (int sub = 0; sub < 2; ++sub)
                #pragma unroll
                for (int ks = 0; ks < 4; ++ks)
                    kf[sub][ks] = *reinterpret_cast<const bf16x8*>(
                        &Kh[(size_t)(kv0 + sub * 32 + l31) * 64 + ks * 16 + hi * 8]);

            // V fragments (A of O^T) — issued early, consumed after softmax
            bf16x8 vf[2][4];
            #pragma unroll
            for (int d = 0; d < 2; ++d)
                #pragma unroll
                for (int ks = 0; ks < 4; ++ks)
                    vf[d][ks] = *reinterpret_cast<const bf16x8*>(
                        &Vh[(size_t)(d * 32 + l31) * TSEQ + kv0 + ks * 16 + hi * 8]);

            // S^T = K · Q^T  (rows = kv, cols = q)
            f32x16 s0 = {}, s1 = {};
            #pragma unroll
            for (int ks = 0; ks < 4; ++ks) {
                s0 = mfma32(kf[0][ks], qf[ks], s0);
                s1 = mfma32(kf[1][ks], qf[ks], s1);
            }

            float sv[32];
            #pragma unroll
            for (int i = 0; i < 16; ++i) { sv[i] = s0[i]; sv[16 + i] = s1[i]; }

            if (kt == ntiles - 1) {           // diagonal tile: causal mask
                const int qrel = q0 + l31 - kv0;
                const int h4 = hi * 4;
                #pragma unroll
                for (int i = 0; i < 32; ++i) {
                    int kvbase = (i >> 4) * 32 + (i & 3) + 8 * ((i >> 2) & 3);
                    if (kvbase + h4 > qrel) sv[i] = -1e30f;
                }
            }

            // row max: in-lane tree + cross-half swap
            float t[16];
            #pragma unroll
            for (int i = 0; i < 16; ++i) t[i] = fmaxf(sv[i], sv[i + 16]);
            #pragma unroll
            for (int ss = 8; ss >= 1; ss >>= 1)
                #pragma unroll
                for (int i = 0; i < ss; ++i) t[i] = fmaxf(t[i], t[i + ss]);
            float pmax;
            {
                union { float f; unsigned u; } c; c.f = t[0];
                u32x2 r = __builtin_amdgcn_permlane32_swap(c.u, c.u, false, false);
                union { unsigned u; float f; } ra, rb; ra.u = r.x; rb.u = r.y;
                pmax = fmaxf(ra.f, rb.f);
            }

            // defer-max (T13): only rescale when row max grows past mrun + 8
            if (!__all(pmax <= mrun + 8.0f)) {
                float mnew = fmaxf(mrun, pmax);
                float corr = exp2f(mrun - mnew);
                #pragma unroll
                for (int i = 0; i < 16; ++i) { o0[i] *= corr; o1[i] *= corr; }
                lrun *= corr;
                mrun = mnew;
            }

            float e[32];
            #pragma unroll
            for (int i = 0; i < 32; ++i) e[i] = exp2f(sv[i] - mrun);

            // row sum: in-lane tree + cross-half swap
            float u[16];
            #pragma unroll
            for (int i = 0; i < 16; ++i) u[i] = e[i] + e[i + 16];
            #pragma unroll
            for (int ss = 8; ss >= 1; ss >>= 1)
                #pragma unroll
                for (int i = 0; i < ss; ++i) u[i] += u[i + ss];
            float ps;
            {
                union { float f; unsigned u; } c; c.f = u[0];
                u32x2 r = __builtin_amdgcn_permlane32_swap(c.u, c.u, false, false);
                union { unsigned u; float f; } ra, rb; ra.u = r.x; rb.u = r.y;
                ps = ra.f + rb.f;
            }
            lrun += ps;

            // pack P^T B-fragments: per 16-kv step, 4 cvt_pk + 2 permlane
            bf16x8 pw[4];
            #pragma unroll
            for (int ks = 0; ks < 4; ++ks) {
                const int eb = (ks >> 1) * 16 + (ks & 1) * 8;
                u32x2 r02 = __builtin_amdgcn_permlane32_swap(
                    cvt_pk_bf16(e[eb + 0], e[eb + 1]), cvt_pk_bf16(e[eb + 4], e[eb + 5]),
                    false, false);
                u32x2 r13 = __builtin_amdgcn_permlane32_swap(
                    cvt_pk_bf16(e[eb + 2], e[eb + 3]), cvt_pk_bf16(e[eb + 6], e[eb + 7]),
                    false, false);
                union { unsigned wd[4]; bf16x8 v; } pk;
                pk.wd[0] = r02.x; pk.wd[1] = r13.x; pk.wd[2] = r02.y; pk.wd[3] = r13.y;
                pw[ks] = pk.v;
            }

            // O^T += V^T · P^T
            #pragma unroll
            for (int ks = 0; ks < 4; ++ks) {
                o0 = mfma32(vf[0][ks], pw[ks], o0);
                o1 = mfma32(vf[1][ks], pw[ks], o1);
            }
        }

        // ---- in-block 4->1 merge (waves 1-3 dump, wave 0 combines) ----
        __syncthreads();                 // slots free (prev phase merge done)
        if (w > 0) {
            #pragma unroll
            for (int i = 0; i < 16; ++i) {
                Osh[w - 1][i][lane]      = o0[i];
                Osh[w - 1][16 + i][lane] = o1[i];
            }
            Msh[w - 1][lane] = mrun;
            Lsh[w - 1][lane] = lrun;
        }
        __syncthreads();
        if (w == 0) {
            #pragma unroll
            for (int p = 0; p < 3; ++p) {
                float mp = Msh[p][lane], lp = Lsh[p][lane];
                float mn = fmaxf(mrun, mp);
                float a = exp2f(mrun - mn), b = exp2f(mp - mn);
                #pragma unroll
                for (int i = 0; i < 16; ++i) {
                    o0[i] = o0[i] * a + Osh[p][i][lane] * b;
                    o1[i] = o1[i] * a + Osh[p][16 + i][lane] * b;
                }
                lrun = lrun * a + lp * b;
                mrun = mn;
            }

            // epilogue: y[t][h*64+d], d = dsub*32 + (rr&3)+8*(rr>>2)+4*hi
            float inv = 1.0f / lrun;
            const int trow = q0 + l31;
            #pragma unroll
            for (int d = 0; d < 2; ++d) {
                #pragma unroll
                for (int p = 0; p < 8; ++p) {
                    const int rr = p * 2;
                    float v0 = (d ? o1 : o0)[rr] * inv;
                    float v1 = (d ? o1 : o0)[rr + 1] * inv;
                    int c = h * 64 + d * 32 + (rr & 3) + 8 * (rr >> 2) + hi * 4;
                    unsigned wd = cvt_pk_bf16(v0, v1);
                    *reinterpret_cast<unsigned*>(
                        const_cast<unsigned short*>(&Y[(size_t)trow * CDIM + c])) = wd;
                }
            }
        }
    }
}

// ---------------- launch ----------------

extern "C" void kernel_launch(void* const* d_in, const int* in_sizes, int n_in,
                              void* d_out, int out_size, void* d_ws, size_t ws_size,
                              hipStream_t stream) {
    const float* x      = (const float*)d_in[0];
    const float* w_attn = (const float*)d_in[1];
    const float* b_attn = (const float*)d_in[2];
    const float* w_proj = (const float*)d_in[3];
    const float* b_proj = (const float*)d_in[4];
    float* out = (float*)d_out;

    char* ws = (char*)d_ws;
    unsigned short* xb  = (unsigned short*)(ws + 0);         // 4096*768
    unsigned short* WaT = (unsigned short*)(ws + 6291456);   // 2304*768
    unsigned short* WpT = (unsigned short*)(ws + 9830400);   // 768*768
    unsigned short* Qb  = (unsigned short*)(ws + 11010048);  // 12*4096*64
    unsigned short* Kb  = (unsigned short*)(ws + 17301504);  // 12*4096*64
    unsigned short* Vt  = (unsigned short*)(ws + 23592960);  // 12*64*4096
    unsigned short* Yb  = (unsigned short*)(ws + 29884416);  // 4096*768

    cvt_f32_bf16<<<2048, 256, 0, stream>>>(x, xb, TSEQ * CDIM / 4);
    transpose_cvt<<<dim3(2304 / 32, 768 / 32), 256, 0, stream>>>(w_attn, WaT, 768, 2304);
    transpose_cvt<<<dim3(768 / 32, 768 / 32), 256, 0, stream>>>(w_proj, WpT, 768, 768);

    // QK part: cols 0..1535 of w_attn
    gemm_bt<0><<<dim3(TSEQ / 128, 1536 / 128), 256, 0, stream>>>(
        xb, WaT, b_attn, Qb, Kb, nullptr, nullptr, TSEQ, 2304, CDIM);
    // V part: cols 1536..2303, swapped-operand (transposed C -> coalesced Vt)
    gemm_bt<2><<<dim3(TSEQ / 128, 768 / 128), 256, 0, stream>>>(
        xb, WaT + (size_t)1536 * 768, b_attn + 1536, nullptr, nullptr, Vt, nullptr,
        TSEQ, 768, CDIM);

    attn_fwd<<<NHEAD * 64, 256, 0, stream>>>(Qb, Kb, Vt, Yb);

    gemm_bt<1><<<dim3(TSEQ / 128, CDIM / 128), 256, 0, stream>>>(
        Yb, WpT, b_proj, nullptr, nullptr, nullptr, out, TSEQ, CDIM, CDIM);
}